// Round 23
// baseline (2137.156 us; speedup 1.0000x reference)
//
#include <hip/hip_runtime.h>

// ---------------------------------------------------------------------------
// 2-layer "bidirectional" LSTM generator, B=2048, T=128, HID=150.
// R23 = R22/R20 (1.90 ms) scaled to ALL 256 CUs: 256 WGs x 8 batch rows/WG.
// Regime: per-XCD, 16 active CUs pulled 25.6 MB/step from a shared 1.6 MB
// L2-resident weight set (~39% of XCD L2 BW). Doubling active CUs doubles
// demand on the SAME footprint (residency preserved; floor ~12 us/step).
// MFMA N stays 16: tile rows 8-15 duplicate rows 0-7 (bounded, no NaN;
// acc columns 8-15 never stored). Output/length guards now l < 8.
// Everything else identical to R22: register ring[5] weights, runtime-ks
// loops (spill-free), biases folded, lgkm-only barriers, acc[5] AGPR.
// LDS: tile 16x1312=20992 | pjl @20992 (10240). Total 31232 B.
// ---------------------------------------------------------------------------

typedef _Float16 f16;
typedef _Float16 f16x8 __attribute__((ext_vector_type(8)));
typedef _Float16 f16x2v __attribute__((ext_vector_type(2)));
typedef float    f32x4 __attribute__((ext_vector_type(4)));

#define LOG2E 1.44269504f

__device__ __forceinline__ float sigm_(float x) {
    float e = __builtin_amdgcn_exp2f(-LOG2E * x);
    return __builtin_amdgcn_rcpf(1.f + e);
}
__device__ __forceinline__ float tanh_(float x) {
    float e = __builtin_amdgcn_exp2f(2.f * LOG2E * x);
    return 1.f - 2.f * __builtin_amdgcn_rcpf(1.f + e);
}

// Phase barrier: drain LDS ops only (tile h coherence); register loads from
// global memory stay in flight (consumers are compiler-tracked via vmcnt).
__device__ __forceinline__ void bar_lgkm() {
    asm volatile("s_waitcnt lgkmcnt(0)" ::: "memory");
    __builtin_amdgcn_s_barrier();
    asm volatile("" ::: "memory");
}

// ---------------- ws layout (bytes) ----------------
#define OFF_CINIT 2621440
#define OFF_WSTR  7864320
#define OFF_PWPJ  9502720

__device__ float dot105(const float* __restrict__ noise,
                        const float* __restrict__ targ,
                        const float* __restrict__ msk,
                        const float* __restrict__ Wrow, int bb) {
    float s = 0.f;
    const float* nz = noise + (size_t)bb * 100;
#pragma unroll 4
    for (int k = 0; k < 100; ++k) s += nz[k] * Wrow[k];
    s += targ[bb*2+0]*Wrow[100] + targ[bb*2+1]*Wrow[101];
    s += msk[bb*3+0]*Wrow[102] + msk[bb*3+1]*Wrow[103] + msk[bb*3+2]*Wrow[104];
    return s;
}

// HINIT tile regions [h1b,_,1@157 | h0f,x,y,1 | h0b,x,y,1 | h1f] + CINIT.
// Replicates torch's (B,1200).view(8,B,150) on the row-major init buffer.
__global__ void k_init(const float* __restrict__ noise, const float* __restrict__ targ,
                       const float* __restrict__ msk,
                       const float* __restrict__ Wih, const float* __restrict__ bih,
                       const float* __restrict__ Wtk, const float* __restrict__ btk,
                       f16* __restrict__ hinit, float* __restrict__ cinitp) {
    int gid = blockIdx.x * 256 + threadIdx.x;   // 2048*1280 exact
    int b = gid / 1280, c = gid % 1280;
    if (c < 640) {
        int reg = c / 160, loc = c % 160;
        float v = 0.f;
        if (loc < 150) {
            int q = (reg == 0) ? 3 : (reg == 1) ? 0 : (reg == 2) ? 1 : 2; // h1b,h0f,h0b,h1f
            size_t i = (size_t)q * 2048 * 150 + (size_t)b * 150 + loc;
            int bb = (int)(i / 1200), rr = (int)(i % 1200);
            v = dot105(noise, targ, msk, Wih + (size_t)rr * 105, bb) + bih[rr];
        } else if (loc == 157) {
            if (reg != 3) v = 1.0f;             // bias column (b_l0/b_l1/b_proj)
        } else if (reg == 1 || reg == 2) {
            if (loc < 152) {                    // x0
                int o = loc - 150;
                v = dot105(noise, targ, msk, Wtk + o * 105, b) + btk[o];
            } else if (loc == 152) v = targ[b*2+0];   // y
            else if (loc == 153)   v = targ[b*2+1];
            else if (loc <= 156)   v = msk[b*3 + (loc - 154)];
        }
        hinit[(size_t)b * 640 + c] = (f16)v;
    } else {
        int idx = c - 640;                       // layer*320 + d*160 + j
        int layer = idx / 320, r = idx % 320, d = r / 160, j = r % 160;
        float v = 0.f;
        if (j < 150) {
            int q = 4 + layer * 2 + d;
            size_t i = (size_t)q * 2048 * 150 + (size_t)b * 150 + j;
            int bb = (int)(i / 1200), rr = (int)(i % 1200);
            v = dot105(noise, targ, msk, Wih + (size_t)rr * 105, bb) + bih[rr];
        }
        cinitp[(((size_t)layer * 2048 + b) * 2 + d) * 160 + j] = v;
    }
}

// Per-wave linear A-frag streams [16][100][512] + proj frags (10 nonzero ks).
__global__ void k_pack(const float* __restrict__ Wih0, const float* __restrict__ Whh0,
                       const float* __restrict__ bl0,
                       const float* __restrict__ Wih1, const float* __restrict__ Whh1,
                       const float* __restrict__ bl1,
                       const float* __restrict__ Wp,   const float* __restrict__ bpj,
                       f16* __restrict__ wstream, f16* __restrict__ pwpj) {
    int gid = blockIdx.x * 256 + threadIdx.x;   // 824,320 exact
    if (gid < 819200) {           // [w][100][64][8]
        int e = gid & 7, l = (gid >> 3) & 63;
        int f = (gid >> 9) % 100, w = gid / 51200;
        int r16 = l & 15, k8 = (l >> 4) * 8 + e;
        float v = 0.f;
        if (f < 25) {             // L0
            int ks = f / 5, m = f % 5;
            int mt = w * 5 + m, d = mt / 40, jt = mt % 40;
            int j = jt * 4 + (r16 >> 2), g = r16 & 3;
            int k = ks * 32 + k8;
            if (j < 150) {
                int R = d * 600 + g * 150 + j;
                if (k < 150)       v = Whh0[(size_t)R * 150 + k];
                else if (k < 157)  v = Wih0[(size_t)R * 7 + (k - 150)]; // x+y
                else if (k == 157) v = bl0[R];
            }
        } else {                  // L1
            int fc = f - 25, ks = fc / 5, m = fc % 5;
            int mt = w * 5 + m, d = mt / 40, jt = mt % 40;
            int j = jt * 4 + (r16 >> 2), g = r16 & 3;
            int k = ks * 32 + k8;
            if (j < 150) {
                int R = d * 600 + g * 150 + j;
                if (d == 0) {    // fwd: [h0f,x,y,1 | h0b,x,y,1 | h1f]
                    if (k < 150)                  v = Wih1[(size_t)R * 300 + k];
                    else if (k == 157)            v = bl1[R];
                    else if (k >= 160 && k < 310) v = Wih1[(size_t)R * 300 + (k - 10)];
                    else if (k >= 320 && k < 470) v = Whh1[(size_t)R * 150 + (k - 320)];
                } else {         // bwd: [h1b,_,1 | h0f,x,y,1 | h0b,x,y,1]
                    if (k < 150)                  v = Whh1[(size_t)R * 150 + k];
                    else if (k >= 160 && k < 310) v = Wih1[(size_t)R * 300 + (k - 160)];
                    else if (k == 317)            v = bl1[R];
                    else if (k >= 320 && k < 470) v = Wih1[(size_t)R * 300 + (k - 170)];
                }
            }
        }
        wstream[gid] = (f16)v;
    } else {                      // proj frags [10][64][8]: ks = ksi<5?ksi:ksi+10
        int pg = gid - 819200;
        int e = pg & 7, l = (pg >> 3) & 63, ksi = pg >> 9;
        int ks = ksi < 5 ? ksi : ksi + 10;
        int r16 = l & 15, k = ks * 32 + (l >> 4) * 8 + e;
        float v = 0.f;
        if (r16 < 2) {            // h1b 0..149 | bpj col 157 | h1f 480..629
            if (k < 150)                  v = Wp[r16 * 300 + 150 + k];
            else if (k == 157)            v = bpj[r16];
            else if (k >= 480 && k < 630) v = Wp[r16 * 300 + (k - 480)];
        }
        pwpj[pg] = (f16)v;
    }
}

// ---------------------------------------------------------------------------
// Main persistent kernel: 256 WGs x 1024 thr (16 waves), 8 batch rows/WG.
// Wave w owns M-tiles [5w,5w+5) (w<8 fwd, w>=8 bwd). Tile rows 8-15 are
// duplicates of 0-7 (bounded; acc cols 8-15 never stored).
// Weights stream global -> register ring[5] (no LDS leg).
// ---------------------------------------------------------------------------
__global__ __launch_bounds__(1024) void lstm_main(
    const f16* __restrict__ hinit, const float* __restrict__ cinit,
    const f16* __restrict__ wstream, const f16* __restrict__ pwpj,
    const int* __restrict__ lengths, float* __restrict__ out) {
    __shared__ f16 lds[15616];
    char* ldsb = (char*)lds;
    const int tid = threadIdx.x;
    const int w = tid >> 6, l = tid & 63;
    const int b0 = blockIdx.x * 8;
    const int l15 = l & 15, lg = l >> 4;
    const int dirw = w >> 3;

    // ---- stage LDS ----
    for (int it = tid; it < 16 * 80; it += 1024) {        // tile <- HINIT
        int row = it / 80, c8 = (it % 80) * 8;
        int b = b0 + (row & 7);                           // rows 8-15 duplicate
        f16x8 v = *(const f16x8*)(hinit + (size_t)b * 640 + c8);
        int byte = row * 1312 + c8 * 2;  byte ^= (row & 7) << 4;
        *(f16x8*)(ldsb + byte) = v;
    }
    if (tid < 640)                                        // pjl (10 KB)
        *(f16x8*)(ldsb + 20992 + tid * 16) = *(const f16x8*)(pwpj + tid * 8);

    const int jb = ((w * 5) % 40) * 4 + lg;               // jj(m) = jb + 4m

    float c0s[5], c1s[5];
#pragma unroll
    for (int m = 0; m < 5; ++m) {
        int b = b0 + (l15 & 7);                           // lanes 8-15 duplicate
        c0s[m] = cinit[((size_t)b * 2 + dirw) * 160 + jb + 4 * m];
        c1s[m] = cinit[(((size_t)2048 + b) * 2 + dirw) * 160 + jb + 4 * m];
    }

    int lenb = 0;
    if (w == 0 && l < 8) lenb = lengths[b0 + l];

    const int baseL0 = 160 + dirw * 160;
    const int baseL1 = dirw ? 0 : 160;
    const int hw1    = dirw ? 0 : 480;
    const f16* wsrc = wstream + (size_t)w * 51200 + l * 8;

    // register ring prologue: frags 0..4
    f16x8 ring[5];
#pragma unroll
    for (int i = 0; i < 5; ++i) ring[i] = *(const f16x8*)(wsrc + (size_t)i * 512);

    __syncthreads();

#pragma unroll 1
    for (int t = 0; t < 128; ++t) {
        f32x4 acc[5];
        // ---- Phase A: L0 GEMM (K=160), frags 0..24 (runtime ks loop) ----
#pragma unroll
        for (int m = 0; m < 5; ++m) acc[m] = (f32x4){0.f, 0.f, 0.f, 0.f};
#pragma unroll 1
        for (int ks = 0; ks < 5; ++ks) {
            int byteb = l15 * 1312 + (baseL0 + ks * 32 + lg * 8) * 2;
            byteb ^= (l15 & 7) << 4;
            f16x8 bfr = *(const f16x8*)(ldsb + byteb);
#pragma unroll
            for (int m = 0; m < 5; ++m) {
                const int F = ks * 5 + m;                 // slot = F%5 = m
                f16x8 aq = ring[m];
                ring[m] = *(const f16x8*)(wsrc + (size_t)(F + 5) * 512); // max 29
                acc[m] = __builtin_amdgcn_mfma_f32_16x16x32_f16(aq, bfr, acc[m], 0, 0, 0);
            }
        }
        bar_lgkm();
        // ---- Phase B: act0 -> h0 into tile ----
#pragma unroll
        for (int m = 0; m < 5; ++m) {
            float gi = sigm_(acc[m][0]);
            float gf = sigm_(acc[m][1]);
            float gg = tanh_(acc[m][2]);
            float go = sigm_(acc[m][3]);
            float c = gf * c0s[m] + gi * gg;
            c0s[m] = c;
            float h = go * tanh_(c);
            if (jb + 4 * m < 150) {
                int byte = l15 * 1312 + (baseL0 + jb + 4 * m) * 2;  byte ^= (l15 & 7) << 4;
                *(f16*)(ldsb + byte) = (f16)h;
            }
        }
        bar_lgkm();
        // ---- Phase C: L1 GEMM (K=480), frags 25..99 (runtime ks loop) ----
#pragma unroll
        for (int m = 0; m < 5; ++m) acc[m] = (f32x4){0.f, 0.f, 0.f, 0.f};
#pragma unroll 1
        for (int ks = 0; ks < 15; ++ks) {
            int byteb = l15 * 1312 + (baseL1 + ks * 32 + lg * 8) * 2;
            byteb ^= (l15 & 7) << 4;
            f16x8 bfr = *(const f16x8*)(ldsb + byteb);
            int frb = 30 + ks * 5;                        // refill base
            if (frb >= 100) frb -= 100;                   // last ks wraps to 0
#pragma unroll
            for (int m = 0; m < 5; ++m) {
                f16x8 aq = ring[m];
                ring[m] = *(const f16x8*)(wsrc + (size_t)(frb + m) * 512);
                acc[m] = __builtin_amdgcn_mfma_f32_16x16x32_f16(aq, bfr, acc[m], 0, 0, 0);
            }
        }
        bar_lgkm();
        // ---- Phase D: act1 -> h1 into tile ----
#pragma unroll
        for (int m = 0; m < 5; ++m) {
            float gi = sigm_(acc[m][0]);
            float gf = sigm_(acc[m][1]);
            float gg = tanh_(acc[m][2]);
            float go = sigm_(acc[m][3]);
            float c = gf * c1s[m] + gi * gg;
            c1s[m] = c;
            float h = go * tanh_(c);
            if (jb + 4 * m < 150) {
                int byte = l15 * 1312 + (hw1 + jb + 4 * m) * 2;  byte ^= (l15 & 7) << 4;
                *(f16*)(ldsb + byte) = (f16)h;
            }
        }
        bar_lgkm();
        // ---- Phase E: proj (10 nonzero ks) + out + x writeback (wave 0) ----
        if (w == 0) {
            f32x4 ap = (f32x4){0.f, 0.f, 0.f, 0.f};
#pragma unroll
            for (int ksi = 0; ksi < 10; ++ksi) {
                int ks = ksi < 5 ? ksi : ksi + 10;
                int byte = l15 * 1312 + (ks * 32 + lg * 8) * 2;  byte ^= (l15 & 7) << 4;
                f16x8 bfp = *(const f16x8*)(ldsb + byte);
                f16x8 a = *(const f16x8*)(ldsb + 20992 + ksi * 1024 + l * 16);
                ap = __builtin_amdgcn_mfma_f32_16x16x32_f16(a, bfp, ap, 0, 0, 0);
            }
            if (l < 8) {
                float o0 = ap[0], o1 = ap[1];
                int b = b0 + l;
                bool live = (t < lenb);
                *(float2*)(out + ((size_t)b * 128 + t) * 2) =
                    make_float2(live ? o0 : 0.f, live ? o1 : 0.f);
                f16x2v xv = {(f16)o0, (f16)o1};
                int byte1 = l * 1312 + 620;  byte1 ^= (l & 7) << 4;   // h0f x
                *(f16x2v*)(ldsb + byte1) = xv;
                int byte2 = l * 1312 + 940;  byte2 ^= (l & 7) << 4;   // h0b x
                *(f16x2v*)(ldsb + byte2) = xv;
                // duplicate rows 8-15 keep x in sync (row = l + 8)
                int byte3 = (l + 8) * 1312 + 620;  byte3 ^= ((l + 8) & 7) << 4;
                *(f16x2v*)(ldsb + byte3) = xv;
                int byte4 = (l + 8) * 1312 + 940;  byte4 ^= ((l + 8) & 7) << 4;
                *(f16x2v*)(ldsb + byte4) = xv;
            }
        }
        bar_lgkm();
    }
}

extern "C" void kernel_launch(void* const* d_in, const int* in_sizes, int n_in,
                              void* d_out, int out_size, void* d_ws, size_t ws_size,
                              hipStream_t stream) {
    const float* noise = (const float*)d_in[0];
    const float* targ  = (const float*)d_in[1];
    const float* msk   = (const float*)d_in[2];
    const int*   lens  = (const int*)d_in[3];
    const float* Wih0  = (const float*)d_in[5];
    const float* Whh0  = (const float*)d_in[6];
    const float* bl0   = (const float*)d_in[7];
    const float* Wih1  = (const float*)d_in[8];
    const float* Whh1  = (const float*)d_in[9];
    const float* bl1   = (const float*)d_in[10];
    const float* Wp    = (const float*)d_in[11];
    const float* bpj   = (const float*)d_in[12];
    const float* Wit   = (const float*)d_in[13];
    const float* bit   = (const float*)d_in[14];
    const float* Wtk   = (const float*)d_in[15];
    const float* btk   = (const float*)d_in[16];

    char* ws = (char*)d_ws;
    f16*   HINIT = (f16*)(ws);
    float* CINIT = (float*)(ws + OFF_CINIT);
    f16*   WSTR  = (f16*)(ws + OFF_WSTR);
    f16*   PWPJ  = (f16*)(ws + OFF_PWPJ);

    hipLaunchKernelGGL(k_init,  dim3(10240), dim3(256), 0, stream,
                       noise, targ, msk, Wit, bit, Wtk, btk, HINIT, CINIT);
    hipLaunchKernelGGL(k_pack,  dim3(3220), dim3(256), 0, stream,
                       Wih0, Whh0, bl0, Wih1, Whh1, bl1, Wp, bpj, WSTR, PWPJ);
    hipLaunchKernelGGL(lstm_main, dim3(256), dim3(1024), 0, stream,
                       HINIT, CINIT, WSTR, PWPJ, lens, (float*)d_out);
}

// Round 24
// 2031.650 us; speedup vs baseline: 1.0519x; 1.0519x over previous
//
#include <hip/hip_runtime.h>

// ---------------------------------------------------------------------------
// 2-layer "bidirectional" LSTM generator, B=2048, T=128, HID=150.
// FINAL (R24) = R22/R20, the measured optimum (1.90 ms).
// Design: batch-partitioned persistent kernel, 128 WGs x 1024 thr (16
// waves), 16 batch rows/WG; wave w owns M-tiles [5w,5w+5) (w<8 fwd, w>=8
// bwd) x one N-tile. Gates packed 4j+{i,f,g,o} on the MFMA M-axis so each
// lane holds all 4 gates of a (j,batch) cell. Weights pre-packed into
// per-wave linear f16 A-frag streams (consumption order) with ALL biases
// folded in (y cols 152-156, 1.0 col 157, b_l0/b_l1/b_proj as weight
// columns); streamed global -> register ring[5], runtime-ks loops
// (spill-free: WRITE 2KB), slot = m compile-time, compiler-managed vmcnt;
// lgkm-only phase barriers keep loads in flight. Weights L2-resident
// (FETCH 10 MB/call). acc[5] AGPR, c-state in regs.
// Falsified alternatives: ring-10 (R21 -62%), 256 CUs (R23 -10%),
// 32/64-row WGs (R15/R13), LDS-DMA ring (R13-R17), SW-pipelined reads
// (R19 0%). Binder: per-CU serial recurrence chain (latency-bound).
// LDS: tile 16x1312=20992 | pjl @20992 (10240). Total 31232 B.
// ---------------------------------------------------------------------------

typedef _Float16 f16;
typedef _Float16 f16x8 __attribute__((ext_vector_type(8)));
typedef _Float16 f16x2v __attribute__((ext_vector_type(2)));
typedef float    f32x4 __attribute__((ext_vector_type(4)));

#define LOG2E 1.44269504f

__device__ __forceinline__ float sigm_(float x) {
    float e = __builtin_amdgcn_exp2f(-LOG2E * x);
    return __builtin_amdgcn_rcpf(1.f + e);
}
__device__ __forceinline__ float tanh_(float x) {
    float e = __builtin_amdgcn_exp2f(2.f * LOG2E * x);
    return 1.f - 2.f * __builtin_amdgcn_rcpf(1.f + e);
}

// Phase barrier: drain LDS ops only (tile h coherence); register loads from
// global memory stay in flight (consumers are compiler-tracked via vmcnt).
__device__ __forceinline__ void bar_lgkm() {
    asm volatile("s_waitcnt lgkmcnt(0)" ::: "memory");
    __builtin_amdgcn_s_barrier();
    asm volatile("" ::: "memory");
}

// ---------------- ws layout (bytes) ----------------
#define OFF_CINIT 2621440
#define OFF_WSTR  7864320
#define OFF_PWPJ  9502720

__device__ float dot105(const float* __restrict__ noise,
                        const float* __restrict__ targ,
                        const float* __restrict__ msk,
                        const float* __restrict__ Wrow, int bb) {
    float s = 0.f;
    const float* nz = noise + (size_t)bb * 100;
#pragma unroll 4
    for (int k = 0; k < 100; ++k) s += nz[k] * Wrow[k];
    s += targ[bb*2+0]*Wrow[100] + targ[bb*2+1]*Wrow[101];
    s += msk[bb*3+0]*Wrow[102] + msk[bb*3+1]*Wrow[103] + msk[bb*3+2]*Wrow[104];
    return s;
}

// HINIT tile regions [h1b,_,1@157 | h0f,x,y,1 | h0b,x,y,1 | h1f] + CINIT.
// Replicates torch's (B,1200).view(8,B,150) on the row-major init buffer.
__global__ void k_init(const float* __restrict__ noise, const float* __restrict__ targ,
                       const float* __restrict__ msk,
                       const float* __restrict__ Wih, const float* __restrict__ bih,
                       const float* __restrict__ Wtk, const float* __restrict__ btk,
                       f16* __restrict__ hinit, float* __restrict__ cinitp) {
    int gid = blockIdx.x * 256 + threadIdx.x;   // 2048*1280 exact
    int b = gid / 1280, c = gid % 1280;
    if (c < 640) {
        int reg = c / 160, loc = c % 160;
        float v = 0.f;
        if (loc < 150) {
            int q = (reg == 0) ? 3 : (reg == 1) ? 0 : (reg == 2) ? 1 : 2; // h1b,h0f,h0b,h1f
            size_t i = (size_t)q * 2048 * 150 + (size_t)b * 150 + loc;
            int bb = (int)(i / 1200), rr = (int)(i % 1200);
            v = dot105(noise, targ, msk, Wih + (size_t)rr * 105, bb) + bih[rr];
        } else if (loc == 157) {
            if (reg != 3) v = 1.0f;             // bias column (b_l0/b_l1/b_proj)
        } else if (reg == 1 || reg == 2) {
            if (loc < 152) {                    // x0
                int o = loc - 150;
                v = dot105(noise, targ, msk, Wtk + o * 105, b) + btk[o];
            } else if (loc == 152) v = targ[b*2+0];   // y
            else if (loc == 153)   v = targ[b*2+1];
            else if (loc <= 156)   v = msk[b*3 + (loc - 154)];
        }
        hinit[(size_t)b * 640 + c] = (f16)v;
    } else {
        int idx = c - 640;                       // layer*320 + d*160 + j
        int layer = idx / 320, r = idx % 320, d = r / 160, j = r % 160;
        float v = 0.f;
        if (j < 150) {
            int q = 4 + layer * 2 + d;
            size_t i = (size_t)q * 2048 * 150 + (size_t)b * 150 + j;
            int bb = (int)(i / 1200), rr = (int)(i % 1200);
            v = dot105(noise, targ, msk, Wih + (size_t)rr * 105, bb) + bih[rr];
        }
        cinitp[(((size_t)layer * 2048 + b) * 2 + d) * 160 + j] = v;
    }
}

// Per-wave linear A-frag streams [16][100][512] + proj frags (10 nonzero ks).
__global__ void k_pack(const float* __restrict__ Wih0, const float* __restrict__ Whh0,
                       const float* __restrict__ bl0,
                       const float* __restrict__ Wih1, const float* __restrict__ Whh1,
                       const float* __restrict__ bl1,
                       const float* __restrict__ Wp,   const float* __restrict__ bpj,
                       f16* __restrict__ wstream, f16* __restrict__ pwpj) {
    int gid = blockIdx.x * 256 + threadIdx.x;   // 824,320 exact
    if (gid < 819200) {           // [w][100][64][8]
        int e = gid & 7, l = (gid >> 3) & 63;
        int f = (gid >> 9) % 100, w = gid / 51200;
        int r16 = l & 15, k8 = (l >> 4) * 8 + e;
        float v = 0.f;
        if (f < 25) {             // L0
            int ks = f / 5, m = f % 5;
            int mt = w * 5 + m, d = mt / 40, jt = mt % 40;
            int j = jt * 4 + (r16 >> 2), g = r16 & 3;
            int k = ks * 32 + k8;
            if (j < 150) {
                int R = d * 600 + g * 150 + j;
                if (k < 150)       v = Whh0[(size_t)R * 150 + k];
                else if (k < 157)  v = Wih0[(size_t)R * 7 + (k - 150)]; // x+y
                else if (k == 157) v = bl0[R];
            }
        } else {                  // L1
            int fc = f - 25, ks = fc / 5, m = fc % 5;
            int mt = w * 5 + m, d = mt / 40, jt = mt % 40;
            int j = jt * 4 + (r16 >> 2), g = r16 & 3;
            int k = ks * 32 + k8;
            if (j < 150) {
                int R = d * 600 + g * 150 + j;
                if (d == 0) {    // fwd: [h0f,x,y,1 | h0b,x,y,1 | h1f]
                    if (k < 150)                  v = Wih1[(size_t)R * 300 + k];
                    else if (k == 157)            v = bl1[R];
                    else if (k >= 160 && k < 310) v = Wih1[(size_t)R * 300 + (k - 10)];
                    else if (k >= 320 && k < 470) v = Whh1[(size_t)R * 150 + (k - 320)];
                } else {         // bwd: [h1b,_,1 | h0f,x,y,1 | h0b,x,y,1]
                    if (k < 150)                  v = Whh1[(size_t)R * 150 + k];
                    else if (k >= 160 && k < 310) v = Wih1[(size_t)R * 300 + (k - 160)];
                    else if (k == 317)            v = bl1[R];
                    else if (k >= 320 && k < 470) v = Wih1[(size_t)R * 300 + (k - 170)];
                }
            }
        }
        wstream[gid] = (f16)v;
    } else {                      // proj frags [10][64][8]: ks = ksi<5?ksi:ksi+10
        int pg = gid - 819200;
        int e = pg & 7, l = (pg >> 3) & 63, ksi = pg >> 9;
        int ks = ksi < 5 ? ksi : ksi + 10;
        int r16 = l & 15, k = ks * 32 + (l >> 4) * 8 + e;
        float v = 0.f;
        if (r16 < 2) {            // h1b 0..149 | bpj col 157 | h1f 480..629
            if (k < 150)                  v = Wp[r16 * 300 + 150 + k];
            else if (k == 157)            v = bpj[r16];
            else if (k >= 480 && k < 630) v = Wp[r16 * 300 + (k - 480)];
        }
        pwpj[pg] = (f16)v;
    }
}

// ---------------------------------------------------------------------------
// Main persistent kernel: 128 WGs x 1024 thr (16 waves), 16 batch rows/WG.
// Wave w owns M-tiles [5w,5w+5) (w<8 fwd, w>=8 bwd) x ONE N-tile.
// Weights stream global -> register ring[5] (no LDS leg).
// ---------------------------------------------------------------------------
__global__ __launch_bounds__(1024) void lstm_main(
    const f16* __restrict__ hinit, const float* __restrict__ cinit,
    const f16* __restrict__ wstream, const f16* __restrict__ pwpj,
    const int* __restrict__ lengths, float* __restrict__ out) {
    __shared__ f16 lds[15616];
    char* ldsb = (char*)lds;
    const int tid = threadIdx.x;
    const int w = tid >> 6, l = tid & 63;
    const int b0 = blockIdx.x * 16;
    const int l15 = l & 15, lg = l >> 4;
    const int dirw = w >> 3;

    // ---- stage LDS ----
    for (int it = tid; it < 16 * 80; it += 1024) {        // tile <- HINIT
        int row = it / 80, c8 = (it % 80) * 8;
        f16x8 v = *(const f16x8*)(hinit + (size_t)(b0 + row) * 640 + c8);
        int byte = row * 1312 + c8 * 2;  byte ^= (row & 7) << 4;
        *(f16x8*)(ldsb + byte) = v;
    }
    if (tid < 640)                                        // pjl (10 KB)
        *(f16x8*)(ldsb + 20992 + tid * 16) = *(const f16x8*)(pwpj + tid * 8);

    const int jb = ((w * 5) % 40) * 4 + lg;               // jj(m) = jb + 4m

    float c0s[5], c1s[5];
#pragma unroll
    for (int m = 0; m < 5; ++m) {
        int b = b0 + l15;
        c0s[m] = cinit[((size_t)b * 2 + dirw) * 160 + jb + 4 * m];
        c1s[m] = cinit[(((size_t)2048 + b) * 2 + dirw) * 160 + jb + 4 * m];
    }

    int lenb = 0;
    if (w == 0 && l < 16) lenb = lengths[b0 + l];

    const int baseL0 = 160 + dirw * 160;
    const int baseL1 = dirw ? 0 : 160;
    const int hw1    = dirw ? 0 : 480;
    const f16* wsrc = wstream + (size_t)w * 51200 + l * 8;

    // register ring prologue: frags 0..4
    f16x8 ring[5];
#pragma unroll
    for (int i = 0; i < 5; ++i) ring[i] = *(const f16x8*)(wsrc + (size_t)i * 512);

    __syncthreads();

#pragma unroll 1
    for (int t = 0; t < 128; ++t) {
        f32x4 acc[5];
        // ---- Phase A: L0 GEMM (K=160), frags 0..24 (runtime ks loop) ----
#pragma unroll
        for (int m = 0; m < 5; ++m) acc[m] = (f32x4){0.f, 0.f, 0.f, 0.f};
#pragma unroll 1
        for (int ks = 0; ks < 5; ++ks) {
            int byteb = l15 * 1312 + (baseL0 + ks * 32 + lg * 8) * 2;
            byteb ^= (l15 & 7) << 4;
            f16x8 bfr = *(const f16x8*)(ldsb + byteb);
#pragma unroll
            for (int m = 0; m < 5; ++m) {
                const int F = ks * 5 + m;                 // slot = F%5 = m
                f16x8 aq = ring[m];
                ring[m] = *(const f16x8*)(wsrc + (size_t)(F + 5) * 512); // max 29
                acc[m] = __builtin_amdgcn_mfma_f32_16x16x32_f16(aq, bfr, acc[m], 0, 0, 0);
            }
        }
        bar_lgkm();
        // ---- Phase B: act0 -> h0 into tile ----
#pragma unroll
        for (int m = 0; m < 5; ++m) {
            float gi = sigm_(acc[m][0]);
            float gf = sigm_(acc[m][1]);
            float gg = tanh_(acc[m][2]);
            float go = sigm_(acc[m][3]);
            float c = gf * c0s[m] + gi * gg;
            c0s[m] = c;
            float h = go * tanh_(c);
            if (jb + 4 * m < 150) {
                int byte = l15 * 1312 + (baseL0 + jb + 4 * m) * 2;  byte ^= (l15 & 7) << 4;
                *(f16*)(ldsb + byte) = (f16)h;
            }
        }
        bar_lgkm();
        // ---- Phase C: L1 GEMM (K=480), frags 25..99 (runtime ks loop) ----
#pragma unroll
        for (int m = 0; m < 5; ++m) acc[m] = (f32x4){0.f, 0.f, 0.f, 0.f};
#pragma unroll 1
        for (int ks = 0; ks < 15; ++ks) {
            int byteb = l15 * 1312 + (baseL1 + ks * 32 + lg * 8) * 2;
            byteb ^= (l15 & 7) << 4;
            f16x8 bfr = *(const f16x8*)(ldsb + byteb);
            int frb = 30 + ks * 5;                        // refill base
            if (frb >= 100) frb -= 100;                   // last ks wraps to 0
#pragma unroll
            for (int m = 0; m < 5; ++m) {
                f16x8 aq = ring[m];
                ring[m] = *(const f16x8*)(wsrc + (size_t)(frb + m) * 512);
                acc[m] = __builtin_amdgcn_mfma_f32_16x16x32_f16(aq, bfr, acc[m], 0, 0, 0);
            }
        }
        bar_lgkm();
        // ---- Phase D: act1 -> h1 into tile ----
#pragma unroll
        for (int m = 0; m < 5; ++m) {
            float gi = sigm_(acc[m][0]);
            float gf = sigm_(acc[m][1]);
            float gg = tanh_(acc[m][2]);
            float go = sigm_(acc[m][3]);
            float c = gf * c1s[m] + gi * gg;
            c1s[m] = c;
            float h = go * tanh_(c);
            if (jb + 4 * m < 150) {
                int byte = l15 * 1312 + (hw1 + jb + 4 * m) * 2;  byte ^= (l15 & 7) << 4;
                *(f16*)(ldsb + byte) = (f16)h;
            }
        }
        bar_lgkm();
        // ---- Phase E: proj (10 nonzero ks) + out + x writeback (wave 0) ----
        if (w == 0) {
            f32x4 ap = (f32x4){0.f, 0.f, 0.f, 0.f};
#pragma unroll
            for (int ksi = 0; ksi < 10; ++ksi) {
                int ks = ksi < 5 ? ksi : ksi + 10;
                int byte = l15 * 1312 + (ks * 32 + lg * 8) * 2;  byte ^= (l15 & 7) << 4;
                f16x8 bfp = *(const f16x8*)(ldsb + byte);
                f16x8 a = *(const f16x8*)(ldsb + 20992 + ksi * 1024 + l * 16);
                ap = __builtin_amdgcn_mfma_f32_16x16x32_f16(a, bfp, ap, 0, 0, 0);
            }
            if (l < 16) {
                float o0 = ap[0], o1 = ap[1];
                int b = b0 + l;
                bool live = (t < lenb);
                *(float2*)(out + ((size_t)b * 128 + t) * 2) =
                    make_float2(live ? o0 : 0.f, live ? o1 : 0.f);
                f16x2v xv = {(f16)o0, (f16)o1};
                int byte1 = l * 1312 + 620;  byte1 ^= (l & 7) << 4;   // h0f x
                *(f16x2v*)(ldsb + byte1) = xv;
                int byte2 = l * 1312 + 940;  byte2 ^= (l & 7) << 4;   // h0b x
                *(f16x2v*)(ldsb + byte2) = xv;
            }
        }
        bar_lgkm();
    }
}

extern "C" void kernel_launch(void* const* d_in, const int* in_sizes, int n_in,
                              void* d_out, int out_size, void* d_ws, size_t ws_size,
                              hipStream_t stream) {
    const float* noise = (const float*)d_in[0];
    const float* targ  = (const float*)d_in[1];
    const float* msk   = (const float*)d_in[2];
    const int*   lens  = (const int*)d_in[3];
    const float* Wih0  = (const float*)d_in[5];
    const float* Whh0  = (const float*)d_in[6];
    const float* bl0   = (const float*)d_in[7];
    const float* Wih1  = (const float*)d_in[8];
    const float* Whh1  = (const float*)d_in[9];
    const float* bl1   = (const float*)d_in[10];
    const float* Wp    = (const float*)d_in[11];
    const float* bpj   = (const float*)d_in[12];
    const float* Wit   = (const float*)d_in[13];
    const float* bit   = (const float*)d_in[14];
    const float* Wtk   = (const float*)d_in[15];
    const float* btk   = (const float*)d_in[16];

    char* ws = (char*)d_ws;
    f16*   HINIT = (f16*)(ws);
    float* CINIT = (float*)(ws + OFF_CINIT);
    f16*   WSTR  = (f16*)(ws + OFF_WSTR);
    f16*   PWPJ  = (f16*)(ws + OFF_PWPJ);

    hipLaunchKernelGGL(k_init,  dim3(10240), dim3(256), 0, stream,
                       noise, targ, msk, Wit, bit, Wtk, btk, HINIT, CINIT);
    hipLaunchKernelGGL(k_pack,  dim3(3220), dim3(256), 0, stream,
                       Wih0, Whh0, bl0, Wih1, Whh1, bl1, Wp, bpj, WSTR, PWPJ);
    hipLaunchKernelGGL(lstm_main, dim3(128), dim3(1024), 0, stream,
                       HINIT, CINIT, WSTR, PWPJ, lens, (float*)d_out);
}